// Round 7
// baseline (7424.875 us; speedup 1.0000x reference)
//
#include <hip/hip_runtime.h>
#include <cstdint>
#include <cstddef>

#define TT   512
#define NWG  512              // 256 compute + 256 aux
#define SLOT 65536            // floats per timestep slot in d_out
#define FINALOFF ((size_t)TT * (size_t)SLOT)

// ws layout (bytes)
#define OFF_M     0                         // M f16: 2 MiB
#define OFF_H1R   2097152                   // h1 ring: 4 x 128 KiB
#define OFF_TH1   (OFF_H1R + 4*131072)
#define OFF_H0    (OFF_TH1 + 131072)
#define OFF_TH0   (OFF_H0 + 131072)
#define OFF_ZR    (OFF_TH0 + 131072)        // z1 ring: 4 x 128 KiB
#define OFF_B0    (OFF_ZR + 4*131072)       // 1024 f32
#define OFF_C1    (OFF_B0 + 4096)           // 1024 f32
#define OFF_CNT   (OFF_C1 + 4096)           // 4 groups * 96 u32 (cntA,+32 cntB,+64 cntX)

typedef _Float16 f16;
typedef unsigned long long ull;
typedef _Float16 v8h __attribute__((ext_vector_type(8)));
typedef float v4f __attribute__((ext_vector_type(4)));

union U2 { ull u[2]; v8h v; };

__device__ __forceinline__ void st2(void* p, f16 v) {
  __hip_atomic_store((unsigned short*)p, __builtin_bit_cast(unsigned short, v),
                     __ATOMIC_RELAXED, __HIP_MEMORY_SCOPE_AGENT);
}
__device__ __forceinline__ f16 ld2(const void* p) {
  unsigned short u = __hip_atomic_load((const unsigned short*)p,
                                       __ATOMIC_RELAXED, __HIP_MEMORY_SCOPE_AGENT);
  return __builtin_bit_cast(f16, u);
}
__device__ __forceinline__ ull ld8(const void* p) {
  return __hip_atomic_load((const ull*)p, __ATOMIC_RELAXED, __HIP_MEMORY_SCOPE_AGENT);
}
__device__ __forceinline__ void poll_ge(const unsigned int* c, unsigned int tgt) {
  while (__hip_atomic_load(c, __ATOMIC_RELAXED, __HIP_MEMORY_SCOPE_AGENT) < tgt)
    __builtin_amdgcn_s_sleep(1);
}
__device__ __forceinline__ void cnt_add(unsigned int* c) {
  __hip_atomic_fetch_add(c, 1u, __ATOMIC_RELAXED, __HIP_MEMORY_SCOPE_AGENT);
}

__device__ __forceinline__ float rcpf(float x) {
#if __has_builtin(__builtin_amdgcn_rcpf)
  return __builtin_amdgcn_rcpf(x);
#else
  return 1.0f / x;
#endif
}
__device__ __forceinline__ float tanhfast(float x) {
  x = fminf(fmaxf(x, -20.0f), 20.0f);
  const float u = __expf(-2.0f * x);
  return 1.0f - 2.0f * u * rcpf(1.0f + u);
}

__global__ void k_init(unsigned int* cnt) {
  if (threadIdx.x < 384) cnt[threadIdx.x] = 0u;
}

// b0[i] = bi0+bh0 ; c1[i] = Wi1.bo0 + bi1 + bh1
__global__ void k_bias(const float* __restrict__ Wi, const float* __restrict__ bi,
                       const float* __restrict__ bh, const float* __restrict__ bo,
                       float* __restrict__ b0, float* __restrict__ c1) {
  const int i = blockIdx.x * 256 + threadIdx.x;
  const float* row = Wi + 1048576 + (size_t)i * 1024;
  float s = 0.f;
  for (int k = 0; k < 1024; k += 4) {
    const float4 w = *(const float4*)&row[k];
    const float4 v = *(const float4*)&bo[k];
    s += w.x * v.x + w.y * v.y + w.z * v.z + w.w * v.w;
  }
  c1[i] = s + bi[1024 + i] + bh[1024 + i];
  b0[i] = bi[i] + bh[i];
}

// M[i][d] = sum_k Wi1[i][k] * Wo0[k][d]   (fp32 compute, f16 store)
__global__ __launch_bounds__(256) void k_gemm_M(const float* __restrict__ Wi,
                                                const float* __restrict__ Wo,
                                                f16* __restrict__ Mh) {
  const float* A = Wi + 1048576;
  const float* B = Wo;
  __shared__ float As[16][68];
  __shared__ float Bs[16][68];
  const int bi = blockIdx.x >> 4, bj = blockIdx.x & 15;
  const int i0 = bi * 64, d0 = bj * 64;
  const int ti = threadIdx.x >> 4, tj = threadIdx.x & 15;
  float acc[4][4] = {};
  for (int kc = 0; kc < 1024; kc += 16) {
    const int r = threadIdx.x >> 2, cg = (threadIdx.x & 3) << 2;
    const float4 av = *(const float4*)&A[(size_t)(i0 + r) * 1024 + kc + cg];
    As[cg + 0][r] = av.x; As[cg + 1][r] = av.y; As[cg + 2][r] = av.z; As[cg + 3][r] = av.w;
    const int c2 = threadIdx.x >> 4, dg = (threadIdx.x & 15) << 2;
    const float4 bv = *(const float4*)&B[(size_t)(kc + c2) * 1024 + d0 + dg];
    *(float4*)&Bs[c2][dg] = bv;
    __syncthreads();
#pragma unroll
    for (int kk = 0; kk < 16; ++kk) {
      float a[4], b[4];
#pragma unroll
      for (int q = 0; q < 4; ++q) { a[q] = As[kk][ti * 4 + q]; b[q] = Bs[kk][tj * 4 + q]; }
#pragma unroll
      for (int p = 0; p < 4; ++p)
#pragma unroll
        for (int q = 0; q < 4; ++q) acc[p][q] += a[p] * b[q];
    }
    __syncthreads();
  }
#pragma unroll
  for (int p = 0; p < 4; ++p)
#pragma unroll
    for (int q = 0; q < 4; ++q)
      Mh[(size_t)(i0 + ti * 4 + p) * 1024 + (size_t)(d0 + tj * 4 + q)] = (f16)acc[p][q];
}

__device__ __forceinline__ void ld_frags(const f16* base, v8h out[8]) {
  ull u0[8], u1[8];
#pragma unroll
  for (int s = 0; s < 8; ++s) { const f16* p = base + s * 32; u0[s] = ld8(p); u1[s] = ld8(p + 4); }
#pragma unroll
  for (int s = 0; s < 8; ++s) { U2 c; c.u[0] = u0[s]; c.u[1] = u1[s]; out[s] = c.v; }
}

// ---- persistent RNN: 256 compute WGs + 256 aux WGs (2 per CU) ----
// compute (bq,jt): A(t): h0 = z1(t) + Wh0*th1(t-1) -> h0, th0 ; cntA++
//                  B(t): h1 = M*h0 + Wh1*th0 + c1  -> h1ring[t&3], th1 ; cntB++
// aux (bq,jt):     prefill z1(0..3); iter i: outs(i-1)=Wo1*h1(i-1)+bo1 ; z1(i+3) ; cntX++
// waits: A(t): cntB>=64t  && cntX>=64*max(1,t-2)   (2 iters of aux slack)
//        B(t): cntA>=64(t+1);  aux iter i: cntB>=64i
__global__ __launch_bounds__(256, 2) void k_rnn(
    const float* __restrict__ x,
    const float* __restrict__ Wi, const float* __restrict__ Wh,
    const float* __restrict__ Wo, const float* __restrict__ bo,
    char* __restrict__ ws, float* __restrict__ dout)
{
  const f16* Mh  = (const f16*)(ws + OFF_M);
  f16* h1r[4] = { (f16*)(ws + OFF_H1R), (f16*)(ws + OFF_H1R + 131072),
                  (f16*)(ws + OFF_H1R + 2*131072), (f16*)(ws + OFF_H1R + 3*131072) };
  f16* th1h = (f16*)(ws + OFF_TH1);
  f16* h0h  = (f16*)(ws + OFF_H0);
  f16* th0h = (f16*)(ws + OFF_TH0);
  f16* zr[4] = { (f16*)(ws + OFF_ZR), (f16*)(ws + OFF_ZR + 131072),
                 (f16*)(ws + OFF_ZR + 2*131072), (f16*)(ws + OFF_ZR + 3*131072) };
  const float* b0p = (const float*)(ws + OFF_B0);
  const float* c1p = (const float*)(ws + OFF_C1);

  const int wg = blockIdx.x;
  const bool is_aux = (wg >= 256);
  const int p = is_aux ? (wg - 256) : wg;
  const int bq = p & 3;
  const int jt = p >> 2;
  const int j0 = jt * 16;
  const int tid = threadIdx.x;
  const int l = tid & 63, w = tid >> 6;
  const int lj = l & 15, lk = l >> 4;
  const int jrow = j0 + lj;
  const int rb = tid >> 4, rj = tid & 15;

  unsigned int* cntA = (unsigned int*)(ws + OFF_CNT) + bq * 96;
  unsigned int* cntB = cntA + 32;
  unsigned int* cntX = cntA + 64;

  __shared__ __align__(16) f16 WiL[16 * 1032];
  __shared__ float red[1024];

  const size_t actbase = (size_t)(bq * 16 + lj) * 1024 + (size_t)(w * 256 + lk * 8);
  const int redw = w * 256 + lk * 64 + lj;
  const size_t rdst = (size_t)(bq * 16 + rb) * 1024 + (size_t)(j0 + rj);

  if (!is_aux) {
    // ================= COMPUTE =================
    v8h wWh0[8], wM[8], wWh1[8];
#pragma unroll
    for (int s = 0; s < 8; ++s) {
      const int k0 = w * 256 + s * 32 + lk * 8;
      {
        const float* pp = &Wh[(size_t)jrow * 1024 + k0];
        float4 a = *(const float4*)pp, b = *(const float4*)(pp + 4);
        wWh0[s] = (v8h){(f16)a.x,(f16)a.y,(f16)a.z,(f16)a.w,(f16)b.x,(f16)b.y,(f16)b.z,(f16)b.w};
      }
      {
        const float* pp = &Wh[1048576 + (size_t)jrow * 1024 + k0];
        float4 a = *(const float4*)pp, b = *(const float4*)(pp + 4);
        wWh1[s] = (v8h){(f16)a.x,(f16)a.y,(f16)a.z,(f16)a.w,(f16)b.x,(f16)b.y,(f16)b.z,(f16)b.w};
      }
      wM[s] = *(const v8h*)&Mh[(size_t)jrow * 1024 + k0];
    }
    // pin weight fragments in VGPRs (opaque to remat/sink)
#pragma unroll
    for (int s = 0; s < 8; ++s) {
      asm volatile("" : "+v"(wWh0[s]), "+v"(wM[s]), "+v"(wWh1[s]));
    }
    const float c1v = c1p[j0 + rj];

    for (int t = 0; t < TT; ++t) {
      // ---- wait A ----
      if (tid == 0)      poll_ge(cntB, 64u * (unsigned)t);
      else if (tid == 1) poll_ge(cntX, 64u * (t >= 3 ? (unsigned)(t - 2) : 1u));
      __syncthreads();

      // ---- phase A: h0 = z1(t) + Wh0 * th1(t-1) ----
      const f16 zv = ld2(&zr[t & 3][rdst]);
      v4f acc = {0.f, 0.f, 0.f, 0.f};
      if (t > 0) {
        v8h thf[8];
        ld_frags(th1h + actbase, thf);
#pragma unroll
        for (int s = 0; s < 8; ++s)
          acc = __builtin_amdgcn_mfma_f32_16x16x32_f16(thf[s], wWh0[s], acc, 0, 0, 0);
      }
#pragma unroll
      for (int q = 0; q < 4; ++q) red[redw + q * 16] = acc[q];
      __syncthreads();
      const float h0 = red[tid] + red[256 + tid] + red[512 + tid] + red[768 + tid] + (float)zv;
      st2(&h0h[rdst], (f16)h0);
      st2(&th0h[rdst], (f16)tanhfast(h0));
      asm volatile("s_waitcnt vmcnt(0)" ::: "memory");
      __syncthreads();
      if (tid == 0) cnt_add(cntA);

      // ---- wait B ----
      if (tid == 0) poll_ge(cntA, 64u * (unsigned)(t + 1));
      __syncthreads();

      // ---- phase B: h1 = M*h0 + Wh1*th0 + c1 ----
      v8h g0f[8], t0f[8];
      ld_frags(h0h + actbase, g0f);
      ld_frags(th0h + actbase, t0f);
      v4f aM = {0.f, 0.f, 0.f, 0.f}, aW = {0.f, 0.f, 0.f, 0.f};
#pragma unroll
      for (int s = 0; s < 8; ++s) {
        aM = __builtin_amdgcn_mfma_f32_16x16x32_f16(g0f[s], wM[s], aM, 0, 0, 0);
        aW = __builtin_amdgcn_mfma_f32_16x16x32_f16(t0f[s], wWh1[s], aW, 0, 0, 0);
      }
#pragma unroll
      for (int q = 0; q < 4; ++q) red[redw + q * 16] = aM[q] + aW[q];
      __syncthreads();
      const float h1 = red[tid] + red[256 + tid] + red[512 + tid] + red[768 + tid] + c1v;
      st2(&h1r[t & 3][rdst], (f16)h1);
      const float th1v = tanhfast(h1);
      st2(&th1h[rdst], (f16)th1v);
      if (t == TT - 1) dout[FINALOFF + rdst] = th1v;
      asm volatile("s_waitcnt vmcnt(0)" ::: "memory");
      __syncthreads();
      if (tid == 0) cnt_add(cntB);
    }
  } else {
    // ================= AUX =================
    v8h wWo1[8];
#pragma unroll
    for (int s = 0; s < 8; ++s) {
      const int k0 = w * 256 + s * 32 + lk * 8;
      const float* pp = &Wo[1048576 + (size_t)jrow * 1024 + k0];
      float4 a = *(const float4*)pp, b = *(const float4*)(pp + 4);
      wWo1[s] = (v8h){(f16)a.x,(f16)a.y,(f16)a.z,(f16)a.w,(f16)b.x,(f16)b.y,(f16)b.z,(f16)b.w};
    }
#pragma unroll
    for (int s = 0; s < 8; ++s) { asm volatile("" : "+v"(wWo1[s])); }
    // Wi0 row tile -> LDS (f16)
    for (int u = tid; u < 4096; u += 256) {
      const int rr = u >> 8, c4 = (u & 255) << 2;
      const float4 v = *(const float4*)&Wi[(size_t)(j0 + rr) * 1024 + c4];
      f16* dst = &WiL[rr * 1032 + c4];
      dst[0] = (f16)v.x; dst[1] = (f16)v.y; dst[2] = (f16)v.z; dst[3] = (f16)v.w;
    }
    const float b0v = b0p[j0 + rj];
    const float bo1v = bo[1024 + j0 + rj];
    __syncthreads();

    auto zmake = [&](const float* xt, f16* zdst) {
      __syncthreads();                   // red WAR guard
      v4f az = {0.f, 0.f, 0.f, 0.f};
#pragma unroll
      for (int s = 0; s < 8; ++s) {
        const float* pp = xt + actbase + s * 32;
        const float4 a = *(const float4*)pp;
        const float4 b = *(const float4*)(pp + 4);
        const v8h af = {(f16)a.x,(f16)a.y,(f16)a.z,(f16)a.w,
                        (f16)b.x,(f16)b.y,(f16)b.z,(f16)b.w};
        const v8h bf = *(const v8h*)&WiL[lj * 1032 + w * 256 + s * 32 + lk * 8];
        az = __builtin_amdgcn_mfma_f32_16x16x32_f16(af, bf, az, 0, 0, 0);
      }
#pragma unroll
      for (int q = 0; q < 4; ++q) red[redw + q * 16] = az[q];
      __syncthreads();
      const float r = red[tid] + red[256 + tid] + red[512 + tid] + red[768 + tid] + b0v;
      st2(&zdst[rdst], (f16)r);
    };

    // prefill z1(0..3)
    zmake(x, zr[0]);
    zmake(x + SLOT, zr[1]);
    zmake(x + 2 * (size_t)SLOT, zr[2]);
    zmake(x + 3 * (size_t)SLOT, zr[3]);
    asm volatile("s_waitcnt vmcnt(0)" ::: "memory");
    __syncthreads();
    if (tid == 0) cnt_add(cntX);

    for (int i = 1; i <= TT; ++i) {
      const bool dz = (i + 3 <= TT - 1);
      float4 xa[8], xb[8];
      if (dz) {
        const float* xt = x + (size_t)(i + 3) * SLOT;
#pragma unroll
        for (int s = 0; s < 8; ++s) {
          const float* pp = xt + actbase + s * 32;
          xa[s] = *(const float4*)pp;
          xb[s] = *(const float4*)(pp + 4);
        }
      }
      if (tid == 0) poll_ge(cntB, 64u * (unsigned)i);
      __syncthreads();

      // outs(i-1) = Wo1 * h1(i-1) + bo1
      v8h hrf[8];
      ld_frags(h1r[(i - 1) & 3] + actbase, hrf);
      v4f a2 = {0.f, 0.f, 0.f, 0.f};
#pragma unroll
      for (int s = 0; s < 8; ++s)
        a2 = __builtin_amdgcn_mfma_f32_16x16x32_f16(hrf[s], wWo1[s], a2, 0, 0, 0);
#pragma unroll
      for (int q = 0; q < 4; ++q) red[redw + q * 16] = a2[q];
      __syncthreads();
      const float s1 = red[tid] + red[256 + tid] + red[512 + tid] + red[768 + tid] + bo1v;
      dout[(size_t)(i - 1) * SLOT + rdst] = s1;

      if (dz) {
        __syncthreads();                 // red WAR guard
        v4f az = {0.f, 0.f, 0.f, 0.f};
#pragma unroll
        for (int s = 0; s < 8; ++s) {
          const v8h af = {(f16)xa[s].x,(f16)xa[s].y,(f16)xa[s].z,(f16)xa[s].w,
                          (f16)xb[s].x,(f16)xb[s].y,(f16)xb[s].z,(f16)xb[s].w};
          const v8h bf = *(const v8h*)&WiL[lj * 1032 + w * 256 + s * 32 + lk * 8];
          az = __builtin_amdgcn_mfma_f32_16x16x32_f16(af, bf, az, 0, 0, 0);
        }
#pragma unroll
        for (int q = 0; q < 4; ++q) red[redw + q * 16] = az[q];
        __syncthreads();
        const float r = red[tid] + red[256 + tid] + red[512 + tid] + red[768 + tid] + b0v;
        st2(&zr[(i + 3) & 3][rdst], (f16)r);
      }

      asm volatile("s_waitcnt vmcnt(0)" ::: "memory");
      __syncthreads();
      if (tid == 0) cnt_add(cntX);
    }
  }
}

extern "C" void kernel_launch(void* const* d_in, const int* in_sizes, int n_in,
                              void* d_out, int out_size, void* d_ws, size_t ws_size,
                              hipStream_t stream) {
  (void)in_sizes; (void)n_in; (void)out_size; (void)ws_size;
  const float* x  = (const float*)d_in[0];
  const float* Wi = (const float*)d_in[1];
  const float* bi = (const float*)d_in[2];
  const float* Wh = (const float*)d_in[3];
  const float* bh = (const float*)d_in[4];
  const float* Wo = (const float*)d_in[5];
  const float* bo = (const float*)d_in[6];
  char* ws = (char*)d_ws;
  float* out = (float*)d_out;

  k_init<<<1, 512, 0, stream>>>((unsigned int*)(ws + OFF_CNT));
  k_bias<<<4, 256, 0, stream>>>(Wi, bi, bh, bo, (float*)(ws + OFF_B0), (float*)(ws + OFF_C1));
  k_gemm_M<<<256, 256, 0, stream>>>(Wi, Wo, (f16*)(ws + OFF_M));
  k_rnn<<<NWG, 256, 0, stream>>>(x, Wi, Wh, Wo, bo, ws, out);
}

// Round 8
// 6255.185 us; speedup vs baseline: 1.1870x; 1.1870x over previous
//
#include <hip/hip_runtime.h>
#include <cstdint>
#include <cstddef>

#define TT   512
#define NWG  256
#define SLOT 65536            // floats per timestep slot in d_out
#define SLOTB 262144          // bytes per slot
#define FINALOFF ((size_t)TT * (size_t)SLOT)

// ws layout (bytes)
#define OFF_M     0                         // M f16: 2 MiB
#define OFF_H0    2097152                   // 64*1024 f16 each (128 KiB)
#define OFF_TH0   (OFF_H0 + 131072)
#define OFF_TH1   (OFF_TH0 + 131072)
#define OFF_H1A   (OFF_TH1 + 131072)
#define OFF_H1B   (OFF_H1A + 131072)
#define OFF_B0    (OFF_H1B + 131072)        // 1024 f32
#define OFF_C1    (OFF_B0 + 4096)           // 1024 f32
#define OFF_FLAGS (OFF_C1 + 4096)           // 4 groups * 64 u32

typedef _Float16 f16;
typedef unsigned long long ull;
typedef _Float16 v8h __attribute__((ext_vector_type(8)));
typedef float v4f __attribute__((ext_vector_type(4)));

union U2 { ull u[2]; v8h v; };
union P4 { f16 h[4]; ull u; };

__device__ __forceinline__ void st2(void* p, f16 v) {
  __hip_atomic_store((unsigned short*)p, __builtin_bit_cast(unsigned short, v),
                     __ATOMIC_RELAXED, __HIP_MEMORY_SCOPE_AGENT);
}
__device__ __forceinline__ ull ld8(const void* p) {
  return __hip_atomic_load((const ull*)p, __ATOMIC_RELAXED, __HIP_MEMORY_SCOPE_AGENT);
}
__device__ __forceinline__ void ld_frags(const f16* base, v8h out[8]) {
  ull u0[8], u1[8];
#pragma unroll
  for (int s = 0; s < 8; ++s) { const f16* p = base + s * 32; u0[s] = ld8(p); u1[s] = ld8(p + 4); }
#pragma unroll
  for (int s = 0; s < 8; ++s) { U2 c; c.u[0] = u0[s]; c.u[1] = u1[s]; out[s] = c.v; }
}

__device__ __forceinline__ float rcpf(float x) {
#if __has_builtin(__builtin_amdgcn_rcpf)
  return __builtin_amdgcn_rcpf(x);
#else
  return 1.0f / x;
#endif
}
__device__ __forceinline__ float tanhfast(float x) {
  x = fminf(fmaxf(x, -20.0f), 20.0f);
  const float u = __expf(-2.0f * x);
  return 1.0f - 2.0f * u * rcpf(1.0f + u);
}

__global__ void k_init(unsigned int* flags) {
  flags[threadIdx.x] = 0u;  // 256 flags
}

// b0[i] = bi0+bh0 ; c1[i] = Wi1.bo0 + bi1 + bh1
__global__ void k_bias(const float* __restrict__ Wi, const float* __restrict__ bi,
                       const float* __restrict__ bh, const float* __restrict__ bo,
                       float* __restrict__ b0, float* __restrict__ c1) {
  const int i = blockIdx.x * 256 + threadIdx.x;
  const float* row = Wi + 1048576 + (size_t)i * 1024;
  float s = 0.f;
  for (int k = 0; k < 1024; k += 4) {
    const float4 w = *(const float4*)&row[k];
    const float4 v = *(const float4*)&bo[k];
    s += w.x * v.x + w.y * v.y + w.z * v.z + w.w * v.w;
  }
  c1[i] = s + bi[1024 + i] + bh[1024 + i];
  b0[i] = bi[i] + bh[i];
}

// M[i][d] = sum_k Wi1[i][k] * Wo0[k][d]   (fp32 compute, f16 store)
__global__ __launch_bounds__(256) void k_gemm_M(const float* __restrict__ Wi,
                                                const float* __restrict__ Wo,
                                                f16* __restrict__ Mh) {
  const float* A = Wi + 1048576;
  const float* B = Wo;
  __shared__ float As[16][68];
  __shared__ float Bs[16][68];
  const int bi = blockIdx.x >> 4, bj = blockIdx.x & 15;
  const int i0 = bi * 64, d0 = bj * 64;
  const int ti = threadIdx.x >> 4, tj = threadIdx.x & 15;
  float acc[4][4] = {};
  for (int kc = 0; kc < 1024; kc += 16) {
    const int r = threadIdx.x >> 2, cg = (threadIdx.x & 3) << 2;
    const float4 av = *(const float4*)&A[(size_t)(i0 + r) * 1024 + kc + cg];
    As[cg + 0][r] = av.x; As[cg + 1][r] = av.y; As[cg + 2][r] = av.z; As[cg + 3][r] = av.w;
    const int c2 = threadIdx.x >> 4, dg = (threadIdx.x & 15) << 2;
    const float4 bv = *(const float4*)&B[(size_t)(kc + c2) * 1024 + d0 + dg];
    *(float4*)&Bs[c2][dg] = bv;
    __syncthreads();
#pragma unroll
    for (int kk = 0; kk < 16; ++kk) {
      float a[4], b[4];
#pragma unroll
      for (int q = 0; q < 4; ++q) { a[q] = As[kk][ti * 4 + q]; b[q] = Bs[kk][tj * 4 + q]; }
#pragma unroll
      for (int p = 0; p < 4; ++p)
#pragma unroll
        for (int q = 0; q < 4; ++q) acc[p][q] += a[p] * b[q];
    }
    __syncthreads();
  }
#pragma unroll
  for (int p = 0; p < 4; ++p)
#pragma unroll
    for (int q = 0; q < 4; ++q)
      Mh[(size_t)(i0 + ti * 4 + p) * 1024 + (size_t)(d0 + tj * 4 + q)] = (f16)acc[p][q];
}

// z1(t) = x(t).Wi0^T + b0, f16, stored group-partitioned inside d_out slot t:
// byte(t,b,j) = t*SLOTB + (b>>4)*65536 + (b&15)*2048 + j*2
// one WG per t; x(t) staged to LDS f16; wave w covers j in [w*256, w*256+256)
__global__ __launch_bounds__(256, 1) void k_z1(const float* __restrict__ x,
                                               const float* __restrict__ Wi,
                                               const float* __restrict__ b0p,
                                               float* __restrict__ dout) {
  const int t = blockIdx.x;
  const int tid = threadIdx.x, l = tid & 63, w = tid >> 6;
  const int lj = l & 15, lk = l >> 4;
  __shared__ __align__(16) f16 XL[64 * 1032];   // padded rows (2064 B stride)
  const float* xt = x + (size_t)t * SLOT;
  for (int u = tid; u < 16384; u += 256) {
    const int b = u >> 8, c4 = (u & 255) << 2;
    const float4 v = *(const float4*)&xt[(size_t)b * 1024 + c4];
    P4 p; p.h[0] = (f16)v.x; p.h[1] = (f16)v.y; p.h[2] = (f16)v.z; p.h[3] = (f16)v.w;
    *(ull*)&XL[b * 1032 + c4] = p.u;
  }
  __syncthreads();
  for (int jt = 0; jt < 16; ++jt) {
    const int jb = w * 256 + jt * 16;
    v4f acc[4] = {{0.f,0.f,0.f,0.f},{0.f,0.f,0.f,0.f},{0.f,0.f,0.f,0.f},{0.f,0.f,0.f,0.f}};
    for (int ks = 0; ks < 32; ++ks) {
      const int k0 = ks * 32 + lk * 8;
      const float* p = &Wi[(size_t)(jb + lj) * 1024 + k0];
      const float4 a = *(const float4*)p, b = *(const float4*)(p + 4);
      const v8h wf = {(f16)a.x,(f16)a.y,(f16)a.z,(f16)a.w,
                      (f16)b.x,(f16)b.y,(f16)b.z,(f16)b.w};
#pragma unroll
      for (int bt = 0; bt < 4; ++bt) {
        const v8h xf = *(const v8h*)&XL[(bt * 16 + lj) * 1032 + k0];
        acc[bt] = __builtin_amdgcn_mfma_f32_16x16x32_f16(xf, wf, acc[bt], 0, 0, 0);
      }
    }
    const float bias = b0p[jb + lj];
#pragma unroll
    for (int bt = 0; bt < 4; ++bt)
#pragma unroll
      for (int q = 0; q < 4; ++q) {
        const int b = bt * 16 + lk * 4 + q;
        f16* dst = (f16*)((char*)dout + (size_t)t * SLOTB + (size_t)(b >> 4) * 65536
                          + (size_t)(b & 15) * 2048) + (jb + lj);
        *dst = (f16)(acc[bt][q] + bias);
      }
  }
}

// ---- persistent RNN: 256 WGs (1/CU), weights LDS-resident, 4x64-WG groups ----
// A(t): h0 = z1(t) + Wh0*th1(t-1) -> h0,th0 | winA: out-MFMAs(t-1), z1(t+1) prefetch
// B(t): h1 = M*h0 + Wh1*th0 + c1 -> h1[t&1],th1 | winB: out reduce+store(t-1)
__global__ __launch_bounds__(256, 1) void k_rnn(
    const float* __restrict__ Wh, const float* __restrict__ Wo,
    const float* __restrict__ bo,
    char* __restrict__ ws, float* __restrict__ dout)
{
  const f16* Mh = (const f16*)(ws + OFF_M);
  f16* h0h  = (f16*)(ws + OFF_H0);
  f16* th0h = (f16*)(ws + OFF_TH0);
  f16* th1h = (f16*)(ws + OFF_TH1);
  f16* h1r[2] = { (f16*)(ws + OFF_H1A), (f16*)(ws + OFF_H1B) };
  const float* c1p = (const float*)(ws + OFF_C1);
  unsigned int* flags = (unsigned int*)(ws + OFF_FLAGS);

  const int wg = blockIdx.x;
  const int bq = wg & 3;        // batch quadrant — barrier group
  const int jt = wg >> 2;       // 0..63
  const int j0 = jt * 16;
  const int tid = threadIdx.x;
  const int l = tid & 63, w = tid >> 6;
  const int lj = l & 15, lk = l >> 4;
  const int rb = tid >> 4, rj = tid & 15;
  unsigned int* gf = flags + bq * 64;

  // LDS: 4 weight mats (16 j-rows x 1024 k, [k/8][j][8] f16 tiles) + reduce buf
  __shared__ __align__(16) char WLb[4 * 32768];
  __shared__ float red[1024];

  // stage f32 mats: 0=Wh0, 2=Wh1, 3=Wo1
  {
    const float* srcs[3] = { Wh, Wh + 1048576, Wo + 1048576 };
    const int mi[3] = { 0, 2, 3 };
#pragma unroll
    for (int m = 0; m < 3; ++m) {
      const float* src = srcs[m];
      for (int u = tid; u < 4096; u += 256) {
        const int j = u >> 8, c4 = (u & 255) << 2;
        const float4 v = *(const float4*)&src[(size_t)(j0 + j) * 1024 + c4];
        P4 p; p.h[0] = (f16)v.x; p.h[1] = (f16)v.y; p.h[2] = (f16)v.z; p.h[3] = (f16)v.w;
        *(ull*)(WLb + mi[m] * 32768 + ((c4 >> 3) << 8) + (j << 4) + ((c4 & 4) << 1)) = p.u;
      }
    }
    for (int u = tid; u < 2048; u += 256) {   // M (f16) -> mat 1
      const int j = u >> 7, c8 = (u & 127) << 3;
      const v8h mv = *(const v8h*)&Mh[(size_t)(j0 + j) * 1024 + c8];
      *(v8h*)(WLb + 32768 + ((c8 >> 3) << 8) + (j << 4)) = mv;
    }
  }
  const float c1v = c1p[j0 + rj];
  const float bo1v = bo[1024 + j0 + rj];
  __syncthreads();

  const size_t actbase = (size_t)(bq * 16 + lj) * 1024 + (size_t)(w * 256 + lk * 8);
  const int redw = w * 256 + lk * 64 + lj;
  const size_t rdst = (size_t)(bq * 16 + rb) * 1024 + (size_t)(j0 + rj);
  const int fbase = ((w * 32 + lk) << 8) + (lj << 4);   // frag byte base (s=0)

  auto wfrag = [&](int m, int s) -> v8h {
    return *(const v8h*)(WLb + m * 32768 + fbase + (s << 10));
  };
  auto zptr = [&](int t) -> const f16* {
    return (const f16*)((const char*)dout + (size_t)t * SLOTB + (size_t)bq * 65536
                        + (size_t)rb * 2048) + (j0 + rj);
  };
  auto reduce4 = [&](v4f a) -> float {
    __syncthreads();
#pragma unroll
    for (int q = 0; q < 4; ++q) red[redw + q * 16] = a[q];
    __syncthreads();
    return red[tid] + red[256 + tid] + red[512 + tid] + red[768 + tid];
  };
  auto arrive = [&](unsigned int ph) {
    asm volatile("s_waitcnt vmcnt(0)" ::: "memory");
    __syncthreads();
    if (tid == 0)
      __hip_atomic_store(&gf[jt], ph, __ATOMIC_RELAXED, __HIP_MEMORY_SCOPE_AGENT);
  };
  auto wait = [&](unsigned int ph) {
    if (tid < 64)
      while (__hip_atomic_load(&gf[tid], __ATOMIC_RELAXED, __HIP_MEMORY_SCOPE_AGENT) < ph)
        __builtin_amdgcn_s_sleep(1);
    __syncthreads();
    asm volatile("" ::: "memory");
  };

  float zv = (float)(*zptr(0));
  unsigned int ph = 0;
  v4f a2 = {0.f, 0.f, 0.f, 0.f};

  for (int t = 0; t < TT; ++t) {
    // ---- phase A: h0 = z1(t) + Wh0 * th1(t-1) ----
    v8h hrf[8];
    v4f accA = {0.f, 0.f, 0.f, 0.f};
    if (t > 0) {
      v8h thf[8];
      ld_frags(th1h + actbase, thf);
      ld_frags(h1r[(t - 1) & 1] + actbase, hrf);
#pragma unroll
      for (int s = 0; s < 8; ++s)
        accA = __builtin_amdgcn_mfma_f32_16x16x32_f16(thf[s], wfrag(0, s), accA, 0, 0, 0);
    }
    const float h0 = reduce4(accA) + zv;
    st2(&h0h[rdst], (f16)h0);
    st2(&th0h[rdst], (f16)tanhfast(h0));
    arrive(++ph);
    // ---- window A: out-GEMM MFMAs (t-1) + z1(t+1) prefetch ----
    float zn = 0.f;
    if (t + 1 < TT) zn = (float)(*zptr(t + 1));
    if (t > 0) {
      v4f aa = {0.f, 0.f, 0.f, 0.f};
#pragma unroll
      for (int s = 0; s < 8; ++s)
        aa = __builtin_amdgcn_mfma_f32_16x16x32_f16(hrf[s], wfrag(3, s), aa, 0, 0, 0);
      a2 = aa;
    }
    wait(ph);

    // ---- phase B: h1 = M*h0 + Wh1*th0 + c1 ----
    v8h g0f[8], t0f[8];
    ld_frags(h0h + actbase, g0f);
    ld_frags(th0h + actbase, t0f);
    v4f aM = {0.f, 0.f, 0.f, 0.f}, aW = {0.f, 0.f, 0.f, 0.f};
#pragma unroll
    for (int s = 0; s < 8; ++s) {
      aM = __builtin_amdgcn_mfma_f32_16x16x32_f16(g0f[s], wfrag(1, s), aM, 0, 0, 0);
      aW = __builtin_amdgcn_mfma_f32_16x16x32_f16(t0f[s], wfrag(2, s), aW, 0, 0, 0);
    }
    const float h1 = reduce4(aM + aW) + c1v;
    const float th1v = tanhfast(h1);
    st2(&h1r[t & 1][rdst], (f16)h1);
    st2(&th1h[rdst], (f16)th1v);
    if (t == TT - 1) dout[FINALOFF + rdst] = th1v;   // plain store
    arrive(++ph);
    // ---- window B: out reduce + store (t-1) ----
    if (t > 0)
      dout[(size_t)(t - 1) * SLOT + rdst] = reduce4(a2) + bo1v;   // plain store
    wait(ph);
    zv = zn;
  }

  // ---- epilogue: outs(TT-1) = Wo1 * h1(TT-1) + bo1 ----
  {
    v8h hrf[8];
    ld_frags(h1r[(TT - 1) & 1] + actbase, hrf);
    v4f aa = {0.f, 0.f, 0.f, 0.f};
#pragma unroll
    for (int s = 0; s < 8; ++s)
      aa = __builtin_amdgcn_mfma_f32_16x16x32_f16(hrf[s], wfrag(3, s), aa, 0, 0, 0);
    dout[(size_t)(TT - 1) * SLOT + rdst] = reduce4(aa) + bo1v;
  }
}

extern "C" void kernel_launch(void* const* d_in, const int* in_sizes, int n_in,
                              void* d_out, int out_size, void* d_ws, size_t ws_size,
                              hipStream_t stream) {
  (void)in_sizes; (void)n_in; (void)out_size; (void)ws_size;
  const float* x  = (const float*)d_in[0];
  const float* Wi = (const float*)d_in[1];
  const float* bi = (const float*)d_in[2];
  const float* Wh = (const float*)d_in[3];
  const float* bh = (const float*)d_in[4];
  const float* Wo = (const float*)d_in[5];
  const float* bo = (const float*)d_in[6];
  char* ws = (char*)d_ws;
  float* out = (float*)d_out;

  k_init<<<1, 256, 0, stream>>>((unsigned int*)(ws + OFF_FLAGS));
  k_bias<<<4, 256, 0, stream>>>(Wi, bi, bh, bo, (float*)(ws + OFF_B0), (float*)(ws + OFF_C1));
  k_gemm_M<<<256, 256, 0, stream>>>(Wi, Wo, (f16*)(ws + OFF_M));
  k_z1<<<512, 256, 0, stream>>>(x, Wi, (const float*)(ws + OFF_B0), out);
  k_rnn<<<NWG, 256, 0, stream>>>(Wh, Wo, bo, ws, out);
}